// Round 1
// baseline (22.734 us; speedup 1.0000x reference)
//
#include <hip/hip_runtime.h>

#define LEN   16384
#define NB    128
#define NC    128
#define NTAPS 128
#define LOUT  16513   // LEN + 2*128 - 128 + 1

// ws float layout: [0..127]=S, [128..255]=G0, [256..383]=G1, [384..511]=G2, [512..639]=H

__global__ __launch_bounds__(256) void prep_kernel(
    const float* __restrict__ x, const float* __restrict__ conv_w,
    const float* __restrict__ conv_b, const float* __restrict__ fc_w,
    const float* __restrict__ fc_b, float* __restrict__ ws)
{
    const int blk = blockIdx.x;
    const int tid = threadIdx.x;
    if (blk < NB) {
        // per-batch sum of x[blk, :]
        const float4* x4 = reinterpret_cast<const float4*>(x) + blk * (LEN / 4);
        float s = 0.f;
        #pragma unroll
        for (int i = 0; i < 16; ++i) {
            float4 v = x4[tid + i * 256];
            s += (v.x + v.y) + (v.z + v.w);
        }
        #pragma unroll
        for (int off = 32; off > 0; off >>= 1) s += __shfl_down(s, off, 64);
        __shared__ float part[4];
        if ((tid & 63) == 0) part[tid >> 6] = s;
        __syncthreads();
        if (tid == 0) ws[blk] = (part[0] + part[1]) + (part[2] + part[3]);
    } else {
        // weight-only precompute: G0,G1,G2,H
        if (tid < NTAPS) {
            float g0 = 0.f, g1 = 0.f, g2 = 0.f, h = fc_b[tid];
            for (int c = 0; c < NC; ++c) {
                float f = fc_w[tid * NC + c];
                g0 = fmaf(f, conv_w[c * 3 + 0], g0);
                g1 = fmaf(f, conv_w[c * 3 + 1], g1);
                g2 = fmaf(f, conv_w[c * 3 + 2], g2);
                h  = fmaf(f, conv_b[c], h);
            }
            ws[128 + tid] = g0;
            ws[256 + tid] = g1;
            ws[384 + tid] = g2;
            ws[512 + tid] = h;
        }
    }
}

// load float4 from "padded x" coordinate space: xp[i] = x[i-128] for i in [128, 128+LEN), else 0.
// f is a float4 index into xp space (xp float4 index 32 == x float4 index 0).
template<bool CHECK>
__device__ __forceinline__ float4 ld_xp(const float4* __restrict__ xr4, int f)
{
    if (CHECK) {
        int g  = f - 32;
        int gc = min(max(g, 0), LEN / 4 - 1);
        float4 v = xr4[gc];
        if (g < 0 || g >= LEN / 4) v = make_float4(0.f, 0.f, 0.f, 0.f);
        return v;
    }
    return xr4[f - 32];
}

template<bool CHECK>
__device__ __forceinline__ void fir_compute(const float4* __restrict__ xr4,
                                            const float4* __restrict__ sf4,
                                            float* __restrict__ acc, int t0)
{
    // 16 consecutive outputs per thread; taps in groups of 16;
    // sliding register window of 32 floats over xp[t0+16*kg .. t0+16*kg+31].
    float W[32];
    const int base4 = t0 >> 2;
    #pragma unroll
    for (int q = 0; q < 8; ++q) {
        float4 v = ld_xp<CHECK>(xr4, base4 + q);
        W[4 * q + 0] = v.x; W[4 * q + 1] = v.y;
        W[4 * q + 2] = v.z; W[4 * q + 3] = v.w;
    }
    #pragma unroll
    for (int kg = 0; kg < 8; ++kg) {
        #pragma unroll
        for (int fq = 0; fq < 4; ++fq) {
            float4 f = sf4[kg * 4 + fq];          // LDS broadcast (uniform addr)
            float fv[4] = {f.x, f.y, f.z, f.w};
            #pragma unroll
            for (int i2 = 0; i2 < 4; ++i2) {
                const int i = fq * 4 + i2;        // tap within group, 0..15
                #pragma unroll
                for (int j = 0; j < 16; ++j)
                    acc[j] = fmaf(fv[i2], W[i + j], acc[j]);
            }
        }
        if (kg < 7) {
            #pragma unroll
            for (int m = 0; m < 16; ++m) W[m] = W[m + 16];
            #pragma unroll
            for (int q = 0; q < 4; ++q) {
                float4 v = ld_xp<CHECK>(xr4, base4 + 8 + kg * 4 + q);
                W[16 + 4 * q] = v.x; W[17 + 4 * q] = v.y;
                W[18 + 4 * q] = v.z; W[19 + 4 * q] = v.w;
            }
        }
    }
}

__global__ __launch_bounds__(256) void fir_kernel(
    const float* __restrict__ x, const float* __restrict__ ws,
    float* __restrict__ out)
{
    const int b   = blockIdx.y;
    const int tid = threadIdx.x;

    __shared__ float4 sf4[NTAPS / 4];
    float* sfilt = reinterpret_cast<float*>(sf4);
    if (tid < NTAPS) {
        const float Sb = ws[b];
        const float x0 = x[(size_t)b * LEN];
        const float xl = x[(size_t)b * LEN + LEN - 1];
        const float g0 = ws[128 + tid], g1 = ws[256 + tid];
        const float g2 = ws[384 + tid], h = ws[512 + tid];
        const float invL = 1.0f / (float)LEN;
        sfilt[tid] = h + invL * fmaf(Sb - xl, g0, fmaf(Sb, g1, (Sb - x0) * g2));
    }
    __syncthreads();

    const int t0 = (blockIdx.x * 256 + tid) * 16;
    if (t0 >= LOUT) return;

    const float4* xr4 = reinterpret_cast<const float4*>(x) + (size_t)b * (LEN / 4);
    float acc[16];
    #pragma unroll
    for (int j = 0; j < 16; ++j) acc[j] = 0.f;

    const bool edge = (blockIdx.x == 0) || (blockIdx.x == gridDim.x - 1);
    if (edge) fir_compute<true >(xr4, sf4, acc, t0);
    else      fir_compute<false>(xr4, sf4, acc, t0);

    float* orow = out + (size_t)b * LOUT;
    if (t0 + 16 <= LOUT) {
        #pragma unroll
        for (int j = 0; j < 16; ++j) orow[t0 + j] = acc[j];
    } else {
        for (int j = 0; j < 16 && t0 + j < LOUT; ++j) orow[t0 + j] = acc[j];
    }
}

extern "C" void kernel_launch(void* const* d_in, const int* in_sizes, int n_in,
                              void* d_out, int out_size, void* d_ws, size_t ws_size,
                              hipStream_t stream)
{
    const float* x      = (const float*)d_in[0];
    const float* conv_w = (const float*)d_in[1];
    const float* conv_b = (const float*)d_in[2];
    const float* fc_w   = (const float*)d_in[3];
    const float* fc_b   = (const float*)d_in[4];
    float* ws  = (float*)d_ws;
    float* out = (float*)d_out;

    prep_kernel<<<dim3(NB + 1), 256, 0, stream>>>(x, conv_w, conv_b, fc_w, fc_b, ws);

    dim3 grid((LOUT + 4095) / 4096, NB);   // (5, 128)
    fir_kernel<<<grid, 256, 0, stream>>>(x, ws, out);
}

// Round 2
// 19.662 us; speedup vs baseline: 1.1562x; 1.1562x over previous
//
#include <hip/hip_runtime.h>

#define LEN   16384
#define NB    128
#define NC    128
#define NTAPS 128
#define LOUT  16513          // LEN + 2*128 - 128 + 1
#define NT    13             // output tiles (256 outputs each) per fir block; 5*13 = 65 tiles
#define SPAN  (NT*256 + 144) // 3472 floats of xp staged per block

typedef __attribute__((ext_vector_type(8))) short bf16x8;
typedef __attribute__((ext_vector_type(4))) float f32x4;

// ws float layout: [0..255] partial row sums (2 per batch),
// [256..383]=G0, [384..511]=G1, [512..639]=G2, [640..767]=H

__device__ __forceinline__ unsigned short f2bf(float f) {
    union { float f; unsigned u; } c; c.f = f;
    unsigned r = c.u + 0x7FFF + ((c.u >> 16) & 1);   // RNE
    return (unsigned short)(r >> 16);
}

__global__ __launch_bounds__(256) void prep_kernel(
    const float* __restrict__ x, const float* __restrict__ conv_w,
    const float* __restrict__ conv_b, const float* __restrict__ fc_w,
    const float* __restrict__ fc_b, float* __restrict__ ws)
{
    const int blk = blockIdx.x;
    const int tid = threadIdx.x;
    if (blk < 2 * NB) {
        // half-row sum: batch blk>>1, half blk&1 (8192 floats)
        const float4* x4 = reinterpret_cast<const float4*>(x)
                         + (blk >> 1) * (LEN / 4) + (blk & 1) * (LEN / 8);
        float s = 0.f;
        #pragma unroll
        for (int i = 0; i < 8; ++i) {
            float4 v = x4[tid + i * 256];
            s += (v.x + v.y) + (v.z + v.w);
        }
        #pragma unroll
        for (int off = 32; off > 0; off >>= 1) s += __shfl_down(s, off, 64);
        __shared__ float part[4];
        if ((tid & 63) == 0) part[tid >> 6] = s;
        __syncthreads();
        if (tid == 0) ws[blk] = (part[0] + part[1]) + (part[2] + part[3]);
    } else {
        // weight-only precompute: G0,G1,G2,H
        if (tid < NTAPS) {
            float g0 = 0.f, g1 = 0.f, g2 = 0.f, h = fc_b[tid];
            for (int c = 0; c < NC; ++c) {
                float f = fc_w[tid * NC + c];
                g0 = fmaf(f, conv_w[c * 3 + 0], g0);
                g1 = fmaf(f, conv_w[c * 3 + 1], g1);
                g2 = fmaf(f, conv_w[c * 3 + 2], g2);
                h  = fmaf(f, conv_b[c], h);
            }
            ws[256 + tid] = g0;
            ws[384 + tid] = g1;
            ws[512 + tid] = g2;
            ws[640 + tid] = h;
        }
    }
}

__global__ __launch_bounds__(256) void fir_mfma(
    const float* __restrict__ x, const float* __restrict__ ws,
    float* __restrict__ out)
{
    const int b   = blockIdx.y;
    const int tid = threadIdx.x;
    const int Tbase = blockIdx.x * NT;

    __shared__ unsigned short sxp[SPAN];   // xp tile, bf16
    __shared__ unsigned short fp[288];     // padded shifted filter, bf16; fp[j]=filt[j-128]

    // batch scalars
    const float Sb = ws[2 * b] + ws[2 * b + 1];
    const float x0 = x[(size_t)b * LEN];
    const float xl = x[(size_t)b * LEN + LEN - 1];

    // ---- stage xp[P0 .. P0+SPAN) as bf16 into LDS (coalesced float4 loads) ----
    const int P0 = Tbase * 256;                       // xp float offset of block
    const float4* xr4 = reinterpret_cast<const float4*>(x) + (size_t)b * (LEN / 4);
    #pragma unroll
    for (int r = 0; r < 4; ++r) {
        int i = tid + r * 256;                        // float4 index within span
        if (i < SPAN / 4) {
            int g4 = (P0 >> 2) + i - 32;              // x float4 index (xp = x shifted by 128)
            float4 v = make_float4(0.f, 0.f, 0.f, 0.f);
            if (g4 >= 0 && g4 < LEN / 4) v = xr4[g4];
            ushort4 hv;
            hv.x = f2bf(v.x); hv.y = f2bf(v.y); hv.z = f2bf(v.z); hv.w = f2bf(v.w);
            *reinterpret_cast<ushort4*>(&sxp[4 * i]) = hv;
        }
    }

    // ---- filt -> padded bf16 array fp ----
    if (tid < 128) {
        const float g0 = ws[256 + tid], g1 = ws[384 + tid];
        const float g2 = ws[512 + tid], hh = ws[640 + tid];
        const float invL = 1.0f / (float)LEN;
        float f = hh + invL * fmaf(Sb - xl, g0, fmaf(Sb, g1, (Sb - x0) * g2));
        fp[128 + tid] = f2bf(f);
    } else {
        fp[tid - 128] = 0;                 // j in [0,128)
        if (tid < 160) fp[tid + 128] = 0;  // j in [256,288)
    }
    __syncthreads();

    // ---- build A fragments (shifted filter), once per thread ----
    const int l = tid & 63, w = tid >> 6;
    const int n = l & 15;        // A-row r == B-col n == C-col
    const int g = l >> 4;        // k-group
    bf16x8 afrag[5];
    #pragma unroll
    for (int kb = 0; kb < 5; ++kb)
        #pragma unroll
        for (int hf = 0; hf < 2; ++hf)
            #pragma unroll
            for (int j = 0; j < 4; ++j)
                afrag[kb][hf * 4 + j] =
                    (short)fp[128 + 32 * kb + 16 * hf + 4 * g + j - n];

    // ---- main loop: wave w handles tiles tau = 4*it + w ----
    float* orow = out + (size_t)b * LOUT;
    #pragma unroll
    for (int it = 0; it < 4; ++it) {
        const int tau = it * 4 + w;
        if (tau >= NT) break;                         // wave-uniform
        const int T = Tbase + tau;
        const unsigned short* bp = &sxp[tau * 256 + 16 * n + 4 * g];
        f32x4 acc = {0.f, 0.f, 0.f, 0.f};
        #pragma unroll
        for (int kb = 0; kb < 5; ++kb) {
            ushort4 lo = *reinterpret_cast<const ushort4*>(bp + 32 * kb);
            ushort4 hi = *reinterpret_cast<const ushort4*>(bp + 32 * kb + 16);
            bf16x8 bfrag;
            bfrag[0] = (short)lo.x; bfrag[1] = (short)lo.y;
            bfrag[2] = (short)lo.z; bfrag[3] = (short)lo.w;
            bfrag[4] = (short)hi.x; bfrag[5] = (short)hi.y;
            bfrag[6] = (short)hi.z; bfrag[7] = (short)hi.w;
            acc = __builtin_amdgcn_mfma_f32_16x16x32_bf16(afrag[kb], bfrag, acc, 0, 0, 0);
        }
        const int t0 = 256 * T + 16 * n + 4 * g;
        if (T < 64) {
            orow[t0 + 0] = acc[0];
            orow[t0 + 1] = acc[1];
            orow[t0 + 2] = acc[2];
            orow[t0 + 3] = acc[3];
        } else {
            #pragma unroll
            for (int j = 0; j < 4; ++j)
                if (t0 + j < LOUT) orow[t0 + j] = acc[j];
        }
    }
}

extern "C" void kernel_launch(void* const* d_in, const int* in_sizes, int n_in,
                              void* d_out, int out_size, void* d_ws, size_t ws_size,
                              hipStream_t stream)
{
    const float* x      = (const float*)d_in[0];
    const float* conv_w = (const float*)d_in[1];
    const float* conv_b = (const float*)d_in[2];
    const float* fc_w   = (const float*)d_in[3];
    const float* fc_b   = (const float*)d_in[4];
    float* ws  = (float*)d_ws;
    float* out = (float*)d_out;

    prep_kernel<<<dim3(2 * NB + 1), 256, 0, stream>>>(x, conv_w, conv_b, fc_w, fc_b, ws);

    dim3 grid(5, NB);   // 5 blocks of 13 tiles cover 65 tiles per batch
    fir_mfma<<<grid, 256, 0, stream>>>(x, ws, out);
}

// Round 3
// 17.998 us; speedup vs baseline: 1.2631x; 1.0924x over previous
//
#include <hip/hip_runtime.h>

#define LEN   16384
#define NB    128
#define NTAPS 128
#define LOUT  16513          // LEN + 2*128 - 128 + 1
#define NT    33             // 256-output tiles per block (2 blocks per batch)
#define SPAN  (NT*256 + 144) // 8592 floats of xp staged per block

typedef __attribute__((ext_vector_type(8))) short bf16x8;
typedef __attribute__((ext_vector_type(4))) float f32x4;

__device__ __forceinline__ unsigned short f2bf(float f) {
    union { float f; unsigned u; } c; c.f = f;
    unsigned r = c.u + 0x7FFF + ((c.u >> 16) & 1);   // RNE
    return (unsigned short)(r >> 16);
}

__global__ __launch_bounds__(512) void fused_fir(
    const float* __restrict__ x, const float* __restrict__ conv_w,
    const float* __restrict__ conv_b, const float* __restrict__ fc_w,
    const float* __restrict__ fc_b, float* __restrict__ out)
{
    const int b   = blockIdx.y;
    const int h   = blockIdx.x;          // 0: outputs [0,8448), 1: [8448,16513)
    const int tid = threadIdx.x;

    __shared__ unsigned short sxp[SPAN]; // xp tile, bf16
    __shared__ unsigned short fp[288];   // padded shifted filter, bf16; fp[j]=filt[j-128]
    __shared__ float scw[384];           // conv_w
    __shared__ float scb[128];           // conv_b
    __shared__ float sfb[128];           // fc_b
    __shared__ float parts[8];
    __shared__ float sx0, sxl;

    const float* xr  = x + (size_t)b * LEN;
    const float4* xr4 = reinterpret_cast<const float4*>(xr);

    // ---- stage small weight arrays ----
    if (tid < 384) scw[tid] = conv_w[tid];
    else if (tid < 512) scb[tid - 384] = conv_b[tid - 384];
    if (tid < 128) sfb[tid] = fc_b[tid];
    if (tid == 0) { sx0 = xr[0]; sxl = xr[LEN - 1]; }

    // ---- full-row read: sum + bf16-stage this block's xp span ----
    // span float s corresponds to xp[P0+s], P0 = 8448*h; xp[i] = x[i-128] (zero-pad).
    // float4: s4 = g4 + 32 - 2112*h
    float s = 0.f;
    const int sbase = 32 - 2112 * h;
    #pragma unroll
    for (int p = 0; p < 8; ++p) {
        const int g4 = tid + p * 512;
        float4 v = xr4[g4];
        s += (v.x + v.y) + (v.z + v.w);
        const int s4 = g4 + sbase;
        if (s4 >= 0 && s4 < SPAN / 4) {
            ushort4 hv;
            hv.x = f2bf(v.x); hv.y = f2bf(v.y); hv.z = f2bf(v.z); hv.w = f2bf(v.w);
            *reinterpret_cast<ushort4*>(&sxp[4 * s4]) = hv;
        }
    }
    // zero-fill span pads
    {
        const ushort4 z = {0, 0, 0, 0};
        if (h == 0) {
            if (tid < 32) *reinterpret_cast<ushort4*>(&sxp[4 * tid]) = z;
        } else {
            if (tid < 132) *reinterpret_cast<ushort4*>(&sxp[4 * (2016 + tid)]) = z;
        }
    }

    // ---- fc_w loads for G computation (4 threads per tap t) ----
    const int t = tid >> 2, q = tid & 3;
    const float4* fw4 = reinterpret_cast<const float4*>(fc_w);
    float4 fw[8];
    #pragma unroll
    for (int m = 0; m < 8; ++m) fw[m] = fw4[8 * tid + m];

    // ---- block-wide row sum ----
    #pragma unroll
    for (int off = 32; off > 0; off >>= 1) s += __shfl_down(s, off, 64);
    if ((tid & 63) == 0) parts[tid >> 6] = s;
    __syncthreads();
    float Sb = 0.f;
    #pragma unroll
    for (int i = 0; i < 8; ++i) Sb += parts[i];

    // ---- G0,G1,G2,H partials over c in [32q, 32q+32) ----
    float g0 = 0.f, g1 = 0.f, g2 = 0.f, hh = 0.f;
    #pragma unroll
    for (int m = 0; m < 8; ++m) {
        const float fv[4] = {fw[m].x, fw[m].y, fw[m].z, fw[m].w};
        #pragma unroll
        for (int jj = 0; jj < 4; ++jj) {
            const int c = 32 * q + 4 * m + jj;
            const float f = fv[jj];
            g0 = fmaf(f, scw[3 * c + 0], g0);
            g1 = fmaf(f, scw[3 * c + 1], g1);
            g2 = fmaf(f, scw[3 * c + 2], g2);
            hh = fmaf(f, scb[c], hh);
        }
    }
    g0 += __shfl_xor(g0, 1); g0 += __shfl_xor(g0, 2);
    g1 += __shfl_xor(g1, 1); g1 += __shfl_xor(g1, 2);
    g2 += __shfl_xor(g2, 1); g2 += __shfl_xor(g2, 2);
    hh += __shfl_xor(hh, 1); hh += __shfl_xor(hh, 2);

    if (q == 0) {
        const float invL = 1.0f / (float)LEN;
        const float flt = sfb[t] + hh
            + invL * fmaf(Sb - sxl, g0, fmaf(Sb, g1, (Sb - sx0) * g2));
        fp[128 + t] = f2bf(flt);
    }
    if (q == 1) fp[t] = 0;
    if (q == 2 && t < 32) fp[256 + t] = 0;
    __syncthreads();

    // ---- build A fragments (shifted filter) ----
    const int l = tid & 63, w = tid >> 6;
    const int n = l & 15;        // C-col
    const int g = l >> 4;        // k-group
    bf16x8 afrag[5];
    #pragma unroll
    for (int kb = 0; kb < 5; ++kb)
        #pragma unroll
        for (int hf = 0; hf < 2; ++hf)
            #pragma unroll
            for (int j = 0; j < 4; ++j)
                afrag[kb][hf * 4 + j] =
                    (short)fp[128 + 32 * kb + 16 * hf + 4 * g + j - n];

    // ---- MFMA FIR: wave w handles tiles tau = w + 8*it ----
    float* orow = out + (size_t)b * LOUT;
    #pragma unroll
    for (int it = 0; it < 5; ++it) {
        const int tau = w + 8 * it;
        if (tau >= NT) break;                 // wave-uniform
        const int T = h * NT + tau;           // global tile index
        if (T >= 65) break;                   // T=65 starts past LOUT
        const unsigned short* bp = &sxp[tau * 256 + 16 * n + 4 * g];
        f32x4 acc = {0.f, 0.f, 0.f, 0.f};
        #pragma unroll
        for (int kb = 0; kb < 5; ++kb) {
            ushort4 lo = *reinterpret_cast<const ushort4*>(bp + 32 * kb);
            ushort4 hi = *reinterpret_cast<const ushort4*>(bp + 32 * kb + 16);
            bf16x8 bfrag;
            bfrag[0] = (short)lo.x; bfrag[1] = (short)lo.y;
            bfrag[2] = (short)lo.z; bfrag[3] = (short)lo.w;
            bfrag[4] = (short)hi.x; bfrag[5] = (short)hi.y;
            bfrag[6] = (short)hi.z; bfrag[7] = (short)hi.w;
            acc = __builtin_amdgcn_mfma_f32_16x16x32_bf16(afrag[kb], bfrag, acc, 0, 0, 0);
        }
        const int t0 = 256 * T + 16 * n + 4 * g;
        if (T < 64) {
            orow[t0 + 0] = acc[0];
            orow[t0 + 1] = acc[1];
            orow[t0 + 2] = acc[2];
            orow[t0 + 3] = acc[3];
        } else {
            #pragma unroll
            for (int j = 0; j < 4; ++j)
                if (t0 + j < LOUT) orow[t0 + j] = acc[j];
        }
    }
}

extern "C" void kernel_launch(void* const* d_in, const int* in_sizes, int n_in,
                              void* d_out, int out_size, void* d_ws, size_t ws_size,
                              hipStream_t stream)
{
    const float* x      = (const float*)d_in[0];
    const float* conv_w = (const float*)d_in[1];
    const float* conv_b = (const float*)d_in[2];
    const float* fc_w   = (const float*)d_in[3];
    const float* fc_b   = (const float*)d_in[4];
    float* out = (float*)d_out;

    dim3 grid(2, NB);   // 2 half-row blocks per batch
    fused_fir<<<grid, 512, 0, stream>>>(x, conv_w, conv_b, fc_w, fc_b, out);
}